// Round 1
// baseline (2814.670 us; speedup 1.0000x reference)
//
#include <hip/hip_runtime.h>
#include <math.h>

// Problem constants (B=4096, T=100, F=13, H=100)
#define B_    4096
#define T_    100
#define F_    13
#define H_    100

typedef short bf16x8 __attribute__((ext_vector_type(8)));
typedef float f32x4  __attribute__((ext_vector_type(4)));

// ---- ws layout (bytes), total 651,264 ----
#define O_HIST   0u        // 512
#define O_ROWMAP 512u      // 4096*4
#define O_BIAS0  16896u    // 448*4
#define O_BIAS1  18688u    // 448*4
#define O_B0     20480u    // 4kt * 28672 u16 * 2B = 229376
#define O_B1     249856u   // 7kt * 28672 u16 * 2B = 401408 -> 651264

// B-fragment array layout (u16 units), per layer:
//   idx = (((kt*4 + g)*7 + ct)*2 + pass)*512 + lane*8 + j
// where lane's frag element j holds W_pass[k = kt*32 + (lane>>4)*8 + j]
//                                  [col = g*112 + ct*16 + (lane&15)]
// (cols are gate-major with H padded 100->112; pad cols/k are zero)

__device__ __forceinline__ float sigmoid_f(float v) {
    return 1.0f / (1.0f + __expf(-v));
}
__device__ __forceinline__ float tanh_f(float v) {
    float e = __expf(2.0f * v);
    return 1.0f - 2.0f / (e + 1.0f);
}
// fp32 -> bf16 hi (truncate) + lo (RNE of remainder): hi+lo ~ 2^-17 rel err
__device__ __forceinline__ void split_bf16(float v, unsigned short& hi, unsigned short& lo) {
    unsigned u = __float_as_uint(v);
    hi = (unsigned short)(u >> 16);
    float hf = __uint_as_float(u & 0xFFFF0000u);
    float rem = v - hf;
    unsigned r = __float_as_uint(rem);
    unsigned rnd = r + 0x7FFFu + ((r >> 16) & 1u);
    lo = (unsigned short)(rnd >> 16);
}
__device__ __forceinline__ float bf16_to_f(unsigned short b) {
    return __uint_as_float(((unsigned)b) << 16);
}

// ---------------- prep: counting sort of rows by length ----------------
__global__ void k_hist(const int* __restrict__ len, int* __restrict__ hist) {
    int b = blockIdx.x * blockDim.x + threadIdx.x;
    if (b < B_) atomicAdd(&hist[len[b]], 1);
}
__global__ void k_scan(int* __restrict__ hist) {
    if (threadIdx.x == 0 && blockIdx.x == 0) {
        int acc = 0;
        for (int l = 0; l <= 100; ++l) { int c = hist[l]; hist[l] = acc; acc += c; }
    }
}
__global__ void k_scatter(const int* __restrict__ len, int* __restrict__ hist,
                          int* __restrict__ rowmap) {
    int b = blockIdx.x * blockDim.x + threadIdx.x;
    if (b < B_) {
        int pos = atomicAdd(&hist[len[b]], 1);
        rowmap[pos] = b;
    }
}

// ---------------- prep: biases (gate-major, padded) ----------------
__global__ void k_prep_bias(const float* __restrict__ bih0, const float* __restrict__ bhh0,
                            const float* __restrict__ bih1, const float* __restrict__ bhh1,
                            float* __restrict__ bias0, float* __restrict__ bias1) {
    int idx = blockIdx.x * blockDim.x + threadIdx.x;
    if (idx < 448) {
        int g = idx / 112, cell = idx % 112;
        float v0 = 0.f, v1 = 0.f;
        if (cell < 100) {
            int row = g * 100 + cell;
            v0 = bih0[row] + bhh0[row];
            v1 = bih1[row] + bhh1[row];
        }
        bias0[idx] = v0; bias1[idx] = v1;
    }
}

// ---------------- prep: weights into B-fragment order, bf16 hi/lo ----------
// Layer0 A-k: k<100 -> h0 (Whh0), 100..112 -> x (Wih0), >=113 -> 0
// Layer1 A-k: k<100 -> h0n (Wih1), 100..199 -> h1 (Whh1), >=200 -> 0
__global__ void k_prep_b(const float* __restrict__ Wih0, const float* __restrict__ Whh0,
                         const float* __restrict__ Wih1, const float* __restrict__ Whh1,
                         unsigned short* __restrict__ B0, unsigned short* __restrict__ B1) {
    const int PER_KT = 4 * 7 * 2 * 512;  // 28672 u16 per K-tile
    int idx = blockIdx.x * blockDim.x + threadIdx.x;
    if (idx >= 7 * PER_KT) return;
    int kt = idx / PER_KT;
    int s  = idx % PER_KT;
    int g  = s / 7168;
    int s2 = s % 7168;
    int ct = s2 / 1024;
    int s3 = s2 % 1024;
    int pass = s3 / 512;
    int e  = s3 % 512;
    int lane = e >> 3, j = e & 7;
    int n = lane & 15, q = lane >> 4;
    int k = kt * 32 + q * 8 + j;
    int cell = ct * 16 + n;

    unsigned short hi, lo;
    {   // layer 1
        float w = 0.f;
        if (cell < 100) {
            int row = g * 100 + cell;
            if (k < 100)      w = Wih1[row * 100 + k];
            else if (k < 200) w = Whh1[row * 100 + (k - 100)];
        }
        split_bf16(w, hi, lo);
        B1[idx] = pass ? lo : hi;
    }
    if (kt < 4) {  // layer 0
        float w = 0.f;
        if (cell < 100) {
            int row = g * 100 + cell;
            if (k < 100)      w = Whh0[row * 100 + k];
            else if (k < 113) w = Wih0[row * 13 + (k - 100)];
        }
        split_bf16(w, hi, lo);
        B0[idx] = pass ? lo : hi;
    }
}

// ---------------- main persistent MFMA LSTM ----------------
// 128 blocks x 32 rows. Waves 0..6: cell-tile ct (cells 16ct..16ct+15), all 4
// gates, both M-tiles. Wave 7: x prefetch.
// v2 schedule changes vs v1:
//  * __launch_bounds__(512,1): 256 VGPR/wave (grid=128 on 256 CUs -> the 2nd
//    block slot was unusable; the 128-reg cap caused scratch spills + JIT
//    serialized B-fragment L2 loads).
//  * layer-0 hi B-fragments (16 frags = 64 VGPR) are loop-invariant -> loaded
//    once pre-loop, resident. Layer-0 = P-pass (pure resident, zero loads)
//    then Q-pass (streams the 16 lo frags).
//  * Double-buffered A-state in LDS (p = t&1), 2 barriers/step instead of 4:
//      phase1: GEMM0 reads A0[p]; h0n written to A0[p^1] (for t+1) and A1[p]
//              (for this step); wave7 loads x(t+1) and writes A0[p^1].
//      barrier; phase2: GEMM1 reads A1[p]; h1n written to A1[p^1]; barrier.
//    Every RAW/WAR pair is separated by >=1 barrier. Final h1 of row with
//    length L lives in buffer L&1 (last write at t=L-1 goes to (L-1)^1 parity).
__global__ __launch_bounds__(512, 1) void k_lstm(
    const float* __restrict__ x, const int* __restrict__ lengths,
    const int* __restrict__ rowmap,
    const unsigned short* __restrict__ B0, const unsigned short* __restrict__ B1,
    const float* __restrict__ bias0, const float* __restrict__ bias1,
    const float* __restrict__ Wfc, const float* __restrict__ bfc,
    float* __restrict__ out)
{
    // strides padded (+8 u16) so frag reads are 2-way-conflict max (free)
    __shared__ __align__(16) unsigned short Ah0[2][32 * 136];
    __shared__ __align__(16) unsigned short Al0[2][32 * 136];
    __shared__ __align__(16) unsigned short Ah1[2][32 * 232];
    __shared__ __align__(16) unsigned short Al1[2][32 * 232];
    __shared__ int sRow[32], sLen[32], sTmax;

    const int tid = threadIdx.x;
    const int wv = tid >> 6, lane = tid & 63;

    if (tid < 32) {
        int r = rowmap[blockIdx.x * 32 + tid];
        sRow[tid] = r; sLen[tid] = lengths[r];
    }
    for (int i = tid; i < 32 * 136; i += 512) {
        Ah0[0][i] = 0; Al0[0][i] = 0; Ah0[1][i] = 0; Al0[1][i] = 0;
    }
    for (int i = tid; i < 32 * 232; i += 512) {
        Ah1[0][i] = 0; Al1[0][i] = 0; Ah1[1][i] = 0; Al1[1][i] = 0;
    }
    __syncthreads();   // (pre-1) sRow/sLen + zero-init published
    if (tid == 0) { int m = 0; for (int i = 0; i < 32; ++i) m = max(m, sLen[i]); sTmax = m; }

    // ---- per-wave setup ----
    const int ct = wv, n = lane & 15, q = lane >> 4;
    const int cell = ct * 16 + n;

    float b0v[4], b1v[4];
    int   lenR[8];
    float c0[8], c1[8];
    int offA0[2], offA1[2];
    const unsigned short* B0w = B0 + ct * 1024 + lane * 8;
    const unsigned short* B1w = B1 + ct * 1024 + lane * 8;
    bf16x8 b0h[4][4];   // resident layer-0 hi fragments (loop-invariant)
    if (wv < 7) {
#pragma unroll
        for (int g = 0; g < 4; ++g) {
            b0v[g] = bias0[g * 112 + cell];
            b1v[g] = bias1[g * 112 + cell];
        }
#pragma unroll
        for (int mt = 0; mt < 2; ++mt) {
            offA0[mt] = (mt * 16 + n) * 136 + q * 8;
            offA1[mt] = (mt * 16 + n) * 232 + q * 8;
#pragma unroll
            for (int r = 0; r < 4; ++r) {
                lenR[mt * 4 + r] = sLen[mt * 16 + q * 4 + r];
                c0[mt * 4 + r] = 0.f; c1[mt * 4 + r] = 0.f;
            }
        }
#pragma unroll
        for (int kt = 0; kt < 4; ++kt)
#pragma unroll
            for (int g = 0; g < 4; ++g)
                b0h[kt][g] = *(const bf16x8*)&B0w[(kt * 4 + g) * 7168];
    }

    // wave 7: x loader (32 rows x 13 feats = 416 slots, 7 per lane)
    int xvalid[7]; size_t xg[7]; int xa[7]; float xv[7];
    if (wv == 7) {
#pragma unroll
        for (int i = 0; i < 7; ++i) {
            int e = i * 64 + lane;
            xvalid[i] = (e < 416);
            int r = xvalid[i] ? (e / 13) : 0;
            int f = xvalid[i] ? (e - 13 * r) : 0;
            xg[i] = (size_t)sRow[r] * (T_ * F_) + f;
            xa[i] = r * 136 + 100 + f;
            xv[i] = xvalid[i] ? x[xg[i]] : 0.f;   // t = 0
        }
    }
    __syncthreads();   // (pre-2) sTmax published; zero-init done everywhere
    const int Tmax = sTmax;
    if (wv == 7) {     // write x_0 into buffer 0
#pragma unroll
        for (int i = 0; i < 7; ++i) if (xvalid[i]) {
            unsigned short hi, lo; split_bf16(xv[i], hi, lo);
            Ah0[0][xa[i]] = hi; Al0[0][xa[i]] = lo;
        }
    }
    __syncthreads();   // (pre-3) x_0 published

    for (int t = 0; t < Tmax; ++t) {
        const int p = t & 1, pn = p ^ 1;
        // =============== phase 1: layer-0 (reads A0[p]) ===============
        if (wv < 7) {
            f32x4 P[2][4], Q[2][4];
#pragma unroll
            for (int mt = 0; mt < 2; ++mt)
#pragma unroll
                for (int g = 0; g < 4; ++g) {
                    P[mt][g] = (f32x4){b0v[g], b0v[g], b0v[g], b0v[g]};
                    Q[mt][g] = (f32x4){0.f, 0.f, 0.f, 0.f};
                }
            // P-pass: resident hi weights, zero global loads -> starts at once
#pragma unroll
            for (int kt = 0; kt < 4; ++kt) {
                bf16x8 ah[2];
#pragma unroll
                for (int mt = 0; mt < 2; ++mt)
                    ah[mt] = *(const bf16x8*)&Ah0[p][offA0[mt] + kt * 32];
#pragma unroll
                for (int g = 0; g < 4; ++g)
#pragma unroll
                    for (int mt = 0; mt < 2; ++mt)
                        P[mt][g] = __builtin_amdgcn_mfma_f32_16x16x32_bf16(ah[mt], b0h[kt][g], P[mt][g], 0, 0, 0);
            }
            // Q-pass: al*bh (resident) + ah*bl (streamed lo frags, 16 loads)
#pragma unroll
            for (int kt = 0; kt < 4; ++kt) {
                bf16x8 ah[2], al[2];
#pragma unroll
                for (int mt = 0; mt < 2; ++mt) {
                    ah[mt] = *(const bf16x8*)&Ah0[p][offA0[mt] + kt * 32];
                    al[mt] = *(const bf16x8*)&Al0[p][offA0[mt] + kt * 32];
                }
#pragma unroll
                for (int g = 0; g < 4; ++g) {
                    bf16x8 bl = *(const bf16x8*)&B0w[(kt * 4 + g) * 7168 + 512];
#pragma unroll
                    for (int mt = 0; mt < 2; ++mt) {
                        Q[mt][g] = __builtin_amdgcn_mfma_f32_16x16x32_bf16(al[mt], b0h[kt][g], Q[mt][g], 0, 0, 0);
                        Q[mt][g] = __builtin_amdgcn_mfma_f32_16x16x32_bf16(ah[mt], bl, Q[mt][g], 0, 0, 0);
                    }
                }
            }
            // pointwise + state update
            float hreg[8];
#pragma unroll
            for (int mt = 0; mt < 2; ++mt)
#pragma unroll
                for (int r = 0; r < 4; ++r) {
                    float zi = P[mt][0][r] + Q[mt][0][r];
                    float zf = P[mt][1][r] + Q[mt][1][r];
                    float zg = P[mt][2][r] + Q[mt][2][r];
                    float zo = P[mt][3][r] + Q[mt][3][r];
                    float cn = sigmoid_f(zf) * c0[mt * 4 + r] + sigmoid_f(zi) * tanh_f(zg);
                    float hn = sigmoid_f(zo) * tanh_f(cn);
                    if (t < lenR[mt * 4 + r]) c0[mt * 4 + r] = cn;
                    hreg[mt * 4 + r] = hn;
                }
            // h0n -> A0[pn] (for GEMM0 at t+1) and A1[p] (for GEMM1 this step)
            if (cell < 100) {
#pragma unroll
                for (int mt = 0; mt < 2; ++mt)
#pragma unroll
                    for (int r = 0; r < 4; ++r) {
                        if (t < lenR[mt * 4 + r]) {
                            int m = mt * 16 + q * 4 + r;
                            unsigned short hi, lo; split_bf16(hreg[mt * 4 + r], hi, lo);
                            Ah0[pn][m * 136 + cell] = hi; Al0[pn][m * 136 + cell] = lo;
                            Ah1[p][m * 232 + cell]  = hi; Al1[p][m * 232 + cell]  = lo;
                        }
                    }
            }
        } else {
            // wave 7: load x(t+1) and write into A0[pn] (read next at t+1)
            if (t + 1 < Tmax) {
#pragma unroll
                for (int i = 0; i < 7; ++i)
                    if (xvalid[i]) xv[i] = x[xg[i] + (size_t)(t + 1) * F_];
#pragma unroll
                for (int i = 0; i < 7; ++i) if (xvalid[i]) {
                    unsigned short hi, lo; split_bf16(xv[i], hi, lo);
                    Ah0[pn][xa[i]] = hi; Al0[pn][xa[i]] = lo;
                }
            }
        }
        __syncthreads();   // (A) h0n published in A1[p]
        // =============== phase 2: layer-1 (reads A1[p]) ===============
        if (wv < 7) {
            f32x4 P[2][4], Q[2][4];
#pragma unroll
            for (int mt = 0; mt < 2; ++mt)
#pragma unroll
                for (int g = 0; g < 4; ++g) {
                    P[mt][g] = (f32x4){b1v[g], b1v[g], b1v[g], b1v[g]};
                    Q[mt][g] = (f32x4){0.f, 0.f, 0.f, 0.f};
                }
#pragma unroll
            for (int kt = 0; kt < 7; ++kt) {
                bf16x8 ah[2], al[2];
#pragma unroll
                for (int mt = 0; mt < 2; ++mt) {
                    ah[mt] = *(const bf16x8*)&Ah1[p][offA1[mt] + kt * 32];
                    al[mt] = *(const bf16x8*)&Al1[p][offA1[mt] + kt * 32];
                }
#pragma unroll
                for (int g = 0; g < 4; ++g) {
                    bf16x8 bh = *(const bf16x8*)&B1w[(kt * 4 + g) * 7168];
                    bf16x8 bl = *(const bf16x8*)&B1w[(kt * 4 + g) * 7168 + 512];
#pragma unroll
                    for (int mt = 0; mt < 2; ++mt) {
                        P[mt][g] = __builtin_amdgcn_mfma_f32_16x16x32_bf16(ah[mt], bh, P[mt][g], 0, 0, 0);
                        Q[mt][g] = __builtin_amdgcn_mfma_f32_16x16x32_bf16(al[mt], bh, Q[mt][g], 0, 0, 0);
                        Q[mt][g] = __builtin_amdgcn_mfma_f32_16x16x32_bf16(ah[mt], bl, Q[mt][g], 0, 0, 0);
                    }
                }
            }
            float hreg[8];
#pragma unroll
            for (int mt = 0; mt < 2; ++mt)
#pragma unroll
                for (int r = 0; r < 4; ++r) {
                    float zi = P[mt][0][r] + Q[mt][0][r];
                    float zf = P[mt][1][r] + Q[mt][1][r];
                    float zg = P[mt][2][r] + Q[mt][2][r];
                    float zo = P[mt][3][r] + Q[mt][3][r];
                    float cn = sigmoid_f(zf) * c1[mt * 4 + r] + sigmoid_f(zi) * tanh_f(zg);
                    float hn = sigmoid_f(zo) * tanh_f(cn);
                    if (t < lenR[mt * 4 + r]) c1[mt * 4 + r] = cn;
                    hreg[mt * 4 + r] = hn;
                }
            // h1n -> A1[pn] (read at t+1); frozen rows keep last value in
            // buffer (len&1)
            if (cell < 100) {
#pragma unroll
                for (int mt = 0; mt < 2; ++mt)
#pragma unroll
                    for (int r = 0; r < 4; ++r) {
                        if (t < lenR[mt * 4 + r]) {
                            int m = mt * 16 + q * 4 + r;
                            unsigned short hi, lo; split_bf16(hreg[mt * 4 + r], hi, lo);
                            Ah1[pn][m * 232 + 100 + cell] = hi;
                            Al1[pn][m * 232 + 100 + cell] = lo;
                        }
                    }
            }
        }
        __syncthreads();   // (B) A0[pn] (h0n+x) and A1[pn] (h1n) published
    }

    // final: out[b] = W_fc . h1 + b_fc  (h1 = hi+lo, frozen at len-1; it lives
    // in buffer len&1 since the last write at t=len-1 targeted parity (len-1)^1)
    if (tid < 32) {
        const int par = sLen[tid] & 1;
        float s = bfc[0];
        for (int j = 0; j < 100; ++j) {
            float h = bf16_to_f(Ah1[par][tid * 232 + 100 + j]) +
                      bf16_to_f(Al1[par][tid * 232 + 100 + j]);
            s = fmaf(Wfc[j], h, s);
        }
        out[sRow[tid]] = s;
    }
}

// ---------------- launch ----------------
extern "C" void kernel_launch(void* const* d_in, const int* in_sizes, int n_in,
                              void* d_out, int out_size, void* d_ws, size_t ws_size,
                              hipStream_t stream) {
    const float* x    = (const float*)d_in[0];
    const int*   len  = (const int*)d_in[1];
    const float* Wih0 = (const float*)d_in[2];
    const float* Whh0 = (const float*)d_in[3];
    const float* bih0 = (const float*)d_in[4];
    const float* bhh0 = (const float*)d_in[5];
    const float* Wih1 = (const float*)d_in[6];
    const float* Whh1 = (const float*)d_in[7];
    const float* bih1 = (const float*)d_in[8];
    const float* bhh1 = (const float*)d_in[9];
    const float* Wfc  = (const float*)d_in[10];
    const float* bfc  = (const float*)d_in[11];
    float* out = (float*)d_out;

    char* ws = (char*)d_ws;   // uses 651,264 bytes
    int*            hist   = (int*)(ws + O_HIST);
    int*            rowmap = (int*)(ws + O_ROWMAP);
    float*          bias0  = (float*)(ws + O_BIAS0);
    float*          bias1  = (float*)(ws + O_BIAS1);
    unsigned short* B0     = (unsigned short*)(ws + O_B0);
    unsigned short* B1     = (unsigned short*)(ws + O_B1);

    hipMemsetAsync(hist, 0, 512, stream);
    k_hist<<<16, 256, 0, stream>>>(len, hist);
    k_scan<<<1, 64, 0, stream>>>(hist);
    k_scatter<<<16, 256, 0, stream>>>(len, hist, rowmap);
    k_prep_bias<<<2, 256, 0, stream>>>(bih0, bhh0, bih1, bhh1, bias0, bias1);
    k_prep_b<<<(7 * 28672 + 255) / 256, 256, 0, stream>>>(Wih0, Whh0, Wih1, Whh1, B0, B1);
    k_lstm<<<128, 512, 0, stream>>>(x, len, rowmap, B0, B1, bias0, bias1, Wfc, bfc, out);
}

// Round 2
// 1767.012 us; speedup vs baseline: 1.5929x; 1.5929x over previous
//
#include <hip/hip_runtime.h>
#include <math.h>

// Problem constants (B=4096, T=100, F=13, H=100)
#define B_    4096
#define T_    100
#define F_    13
#define H_    100

typedef short bf16x8 __attribute__((ext_vector_type(8)));
typedef float f32x4  __attribute__((ext_vector_type(4)));

// ---- ws layout (bytes), total 651,264 ----
#define O_HIST   0u        // 512
#define O_ROWMAP 512u      // 4096*4
#define O_BIAS0  16896u    // 448*4
#define O_BIAS1  18688u    // 448*4
#define O_B0     20480u    // 4kt * 28672 u16 * 2B = 229376
#define O_B1     249856u   // 7kt * 28672 u16 * 2B = 401408 -> 651264

// B-fragment array layout (u16 units), per layer:
//   idx = (((kt*4 + g)*7 + ct)*2 + pass)*512 + lane*8 + j
// where lane's frag element j holds W_pass[k = kt*32 + (lane>>4)*8 + j]
//                                  [col = g*112 + ct*16 + (lane&15)]
// (cols are gate-major with H padded 100->112; pad cols/k are zero)

__device__ __forceinline__ float sigmoid_f(float v) {
    return 1.0f / (1.0f + __expf(-v));
}
__device__ __forceinline__ float tanh_f(float v) {
    float e = __expf(2.0f * v);
    return 1.0f - 2.0f / (e + 1.0f);
}
// fp32 -> bf16 hi (truncate) + lo (RNE of remainder): hi+lo ~ 2^-17 rel err
__device__ __forceinline__ void split_bf16(float v, unsigned short& hi, unsigned short& lo) {
    unsigned u = __float_as_uint(v);
    hi = (unsigned short)(u >> 16);
    float hf = __uint_as_float(u & 0xFFFF0000u);
    float rem = v - hf;
    unsigned r = __float_as_uint(rem);
    unsigned rnd = r + 0x7FFFu + ((r >> 16) & 1u);
    lo = (unsigned short)(rnd >> 16);
}
__device__ __forceinline__ float bf16_to_f(unsigned short b) {
    return __uint_as_float(((unsigned)b) << 16);
}

// ---------------- prep: counting sort of rows by length ----------------
__global__ void k_hist(const int* __restrict__ len, int* __restrict__ hist) {
    int b = blockIdx.x * blockDim.x + threadIdx.x;
    if (b < B_) atomicAdd(&hist[len[b]], 1);
}
__global__ void k_scan(int* __restrict__ hist) {
    if (threadIdx.x == 0 && blockIdx.x == 0) {
        int acc = 0;
        for (int l = 0; l <= 100; ++l) { int c = hist[l]; hist[l] = acc; acc += c; }
    }
}
__global__ void k_scatter(const int* __restrict__ len, int* __restrict__ hist,
                          int* __restrict__ rowmap) {
    int b = blockIdx.x * blockDim.x + threadIdx.x;
    if (b < B_) {
        int pos = atomicAdd(&hist[len[b]], 1);
        rowmap[pos] = b;
    }
}

// ---------------- prep: biases (gate-major, padded) ----------------
__global__ void k_prep_bias(const float* __restrict__ bih0, const float* __restrict__ bhh0,
                            const float* __restrict__ bih1, const float* __restrict__ bhh1,
                            float* __restrict__ bias0, float* __restrict__ bias1) {
    int idx = blockIdx.x * blockDim.x + threadIdx.x;
    if (idx < 448) {
        int g = idx / 112, cell = idx % 112;
        float v0 = 0.f, v1 = 0.f;
        if (cell < 100) {
            int row = g * 100 + cell;
            v0 = bih0[row] + bhh0[row];
            v1 = bih1[row] + bhh1[row];
        }
        bias0[idx] = v0; bias1[idx] = v1;
    }
}

// ---------------- prep: weights into B-fragment order, bf16 hi/lo ----------
// Layer0 A-k: k<100 -> h0 (Whh0), 100..112 -> x (Wih0), >=113 -> 0
// Layer1 A-k: k<100 -> h0n (Wih1), 100..199 -> h1 (Whh1), >=200 -> 0
__global__ void k_prep_b(const float* __restrict__ Wih0, const float* __restrict__ Whh0,
                         const float* __restrict__ Wih1, const float* __restrict__ Whh1,
                         unsigned short* __restrict__ B0, unsigned short* __restrict__ B1) {
    const int PER_KT = 4 * 7 * 2 * 512;  // 28672 u16 per K-tile
    int idx = blockIdx.x * blockDim.x + threadIdx.x;
    if (idx >= 7 * PER_KT) return;
    int kt = idx / PER_KT;
    int s  = idx % PER_KT;
    int g  = s / 7168;
    int s2 = s % 7168;
    int ct = s2 / 1024;
    int s3 = s2 % 1024;
    int pass = s3 / 512;
    int e  = s3 % 512;
    int lane = e >> 3, j = e & 7;
    int n = lane & 15, q = lane >> 4;
    int k = kt * 32 + q * 8 + j;
    int cell = ct * 16 + n;

    unsigned short hi, lo;
    {   // layer 1
        float w = 0.f;
        if (cell < 100) {
            int row = g * 100 + cell;
            if (k < 100)      w = Wih1[row * 100 + k];
            else if (k < 200) w = Whh1[row * 100 + (k - 100)];
        }
        split_bf16(w, hi, lo);
        B1[idx] = pass ? lo : hi;
    }
    if (kt < 4) {  // layer 0
        float w = 0.f;
        if (cell < 100) {
            int row = g * 100 + cell;
            if (k < 100)      w = Whh0[row * 100 + k];
            else if (k < 113) w = Wih0[row * 13 + (k - 100)];
        }
        split_bf16(w, hi, lo);
        B0[idx] = pass ? lo : hi;
    }
}

// ---------------- main persistent MFMA LSTM ----------------
// 128 blocks x 32 rows. Waves 0..6: cell-tile ct (cells 16ct..16ct+15), all 4
// gates, both M-tiles. Wave 7: x prefetch.
// v3 changes vs v2 (which regressed via scratch spills at the 128-VGPR cap):
//  * SINGLE accumulator per (mt,g): hi/lo correction MFMAs chain into the same
//    f32x4 C-operand (P = mfma(ah,bh, mfma(al,bh, mfma(ah,bl, P)))). Saves 32
//    VGPRs vs the separate-Q scheme. Audited demand ~120 < 128 -> no spill.
//  * No resident B fragments (v2's b0h residency was the spill source).
//  * Flattened (kt,g) GEMM loops with explicit 1-deep B-frag double-buffer
//    prefetch (static indices after full unroll) to overlap L2 latency.
//  * amdgpu_waves_per_eu(2,2): 8-wave block = exactly 2 waves/EU, so the
//    register budget may legally be 256/wave; if honored, the compiler gets
//    pipelining headroom. Safe either way since demand fits in 128.
//  * Keep v2's double-buffered LDS A-state, 2 barriers/step (HW-verified).
__global__ __attribute__((amdgpu_flat_work_group_size(512, 512), amdgpu_waves_per_eu(2, 2)))
void k_lstm(
    const float* __restrict__ x, const int* __restrict__ lengths,
    const int* __restrict__ rowmap,
    const unsigned short* __restrict__ B0, const unsigned short* __restrict__ B1,
    const float* __restrict__ bias0, const float* __restrict__ bias1,
    const float* __restrict__ Wfc, const float* __restrict__ bfc,
    float* __restrict__ out)
{
    // strides padded (+8 u16) so frag reads are 2-way-conflict max (free)
    __shared__ __align__(16) unsigned short Ah0[2][32 * 136];
    __shared__ __align__(16) unsigned short Al0[2][32 * 136];
    __shared__ __align__(16) unsigned short Ah1[2][32 * 232];
    __shared__ __align__(16) unsigned short Al1[2][32 * 232];
    __shared__ int sRow[32], sLen[32], sTmax;

    const int tid = threadIdx.x;
    const int wv = tid >> 6, lane = tid & 63;

    if (tid < 32) {
        int r = rowmap[blockIdx.x * 32 + tid];
        sRow[tid] = r; sLen[tid] = lengths[r];
    }
    for (int i = tid; i < 32 * 136; i += 512) {
        Ah0[0][i] = 0; Al0[0][i] = 0; Ah0[1][i] = 0; Al0[1][i] = 0;
    }
    for (int i = tid; i < 32 * 232; i += 512) {
        Ah1[0][i] = 0; Al1[0][i] = 0; Ah1[1][i] = 0; Al1[1][i] = 0;
    }
    __syncthreads();   // (pre-1) sRow/sLen + zero-init published
    if (tid == 0) { int m = 0; for (int i = 0; i < 32; ++i) m = max(m, sLen[i]); sTmax = m; }

    // ---- per-wave setup ----
    const int ct = wv, n = lane & 15, q = lane >> 4;
    const int cell = ct * 16 + n;

    float b0v[4], b1v[4];
    int   lenR[8];
    float c0[8], c1[8];
    int offA0[2], offA1[2];
    const unsigned short* B0w = B0 + ct * 1024 + lane * 8;
    const unsigned short* B1w = B1 + ct * 1024 + lane * 8;
    if (wv < 7) {
#pragma unroll
        for (int g = 0; g < 4; ++g) {
            b0v[g] = bias0[g * 112 + cell];
            b1v[g] = bias1[g * 112 + cell];
        }
#pragma unroll
        for (int mt = 0; mt < 2; ++mt) {
            offA0[mt] = (mt * 16 + n) * 136 + q * 8;
            offA1[mt] = (mt * 16 + n) * 232 + q * 8;
#pragma unroll
            for (int r = 0; r < 4; ++r) {
                lenR[mt * 4 + r] = sLen[mt * 16 + q * 4 + r];
                c0[mt * 4 + r] = 0.f; c1[mt * 4 + r] = 0.f;
            }
        }
    }

    // wave 7: x loader (32 rows x 13 feats = 416 slots, 7 per lane)
    int xvalid[7]; size_t xg[7]; int xa[7]; float xv[7];
    if (wv == 7) {
#pragma unroll
        for (int i = 0; i < 7; ++i) {
            int e = i * 64 + lane;
            xvalid[i] = (e < 416);
            int r = xvalid[i] ? (e / 13) : 0;
            int f = xvalid[i] ? (e - 13 * r) : 0;
            xg[i] = (size_t)sRow[r] * (T_ * F_) + f;
            xa[i] = r * 136 + 100 + f;
            xv[i] = xvalid[i] ? x[xg[i]] : 0.f;   // t = 0
        }
    }
    __syncthreads();   // (pre-2) sTmax published; zero-init done everywhere
    const int Tmax = sTmax;
    if (wv == 7) {     // write x_0 into buffer 0
#pragma unroll
        for (int i = 0; i < 7; ++i) if (xvalid[i]) {
            unsigned short hi, lo; split_bf16(xv[i], hi, lo);
            Ah0[0][xa[i]] = hi; Al0[0][xa[i]] = lo;
        }
    }
    __syncthreads();   // (pre-3) x_0 published

    for (int t = 0; t < Tmax; ++t) {
        const int p = t & 1, pn = p ^ 1;
        // =============== phase 1: layer-0 (reads A0[p]) ===============
        if (wv < 7) {
            f32x4 P[2][4];
#pragma unroll
            for (int mt = 0; mt < 2; ++mt)
#pragma unroll
                for (int g = 0; g < 4; ++g)
                    P[mt][g] = (f32x4){b0v[g], b0v[g], b0v[g], b0v[g]};
            bf16x8 bh[2], bl[2], ah[2], al[2];
            bh[0] = *(const bf16x8*)&B0w[0];
            bl[0] = *(const bf16x8*)&B0w[512];
#pragma unroll
            for (int i = 0; i < 16; ++i) {   // i = kt*4 + g
                const int kt = i >> 2, g = i & 3, cb = i & 1, nb = cb ^ 1;
                if (i + 1 < 16) {
                    bh[nb] = *(const bf16x8*)&B0w[(i + 1) * 7168];
                    bl[nb] = *(const bf16x8*)&B0w[(i + 1) * 7168 + 512];
                }
                if (g == 0) {
#pragma unroll
                    for (int mt = 0; mt < 2; ++mt) {
                        ah[mt] = *(const bf16x8*)&Ah0[p][offA0[mt] + kt * 32];
                        al[mt] = *(const bf16x8*)&Al0[p][offA0[mt] + kt * 32];
                    }
                }
#pragma unroll
                for (int mt = 0; mt < 2; ++mt) {
                    f32x4 acc = P[mt][g];
                    acc = __builtin_amdgcn_mfma_f32_16x16x32_bf16(ah[mt], bl[cb], acc, 0, 0, 0);
                    acc = __builtin_amdgcn_mfma_f32_16x16x32_bf16(al[mt], bh[cb], acc, 0, 0, 0);
                    acc = __builtin_amdgcn_mfma_f32_16x16x32_bf16(ah[mt], bh[cb], acc, 0, 0, 0);
                    P[mt][g] = acc;
                }
            }
            // pointwise + state update
            float hreg[8];
#pragma unroll
            for (int mt = 0; mt < 2; ++mt)
#pragma unroll
                for (int r = 0; r < 4; ++r) {
                    float zi = P[mt][0][r];
                    float zf = P[mt][1][r];
                    float zg = P[mt][2][r];
                    float zo = P[mt][3][r];
                    float cn = sigmoid_f(zf) * c0[mt * 4 + r] + sigmoid_f(zi) * tanh_f(zg);
                    float hn = sigmoid_f(zo) * tanh_f(cn);
                    if (t < lenR[mt * 4 + r]) c0[mt * 4 + r] = cn;
                    hreg[mt * 4 + r] = hn;
                }
            // h0n -> A0[pn] (for GEMM0 at t+1) and A1[p] (for GEMM1 this step)
            if (cell < 100) {
#pragma unroll
                for (int mt = 0; mt < 2; ++mt)
#pragma unroll
                    for (int r = 0; r < 4; ++r) {
                        if (t < lenR[mt * 4 + r]) {
                            int m = mt * 16 + q * 4 + r;
                            unsigned short hi, lo; split_bf16(hreg[mt * 4 + r], hi, lo);
                            Ah0[pn][m * 136 + cell] = hi; Al0[pn][m * 136 + cell] = lo;
                            Ah1[p][m * 232 + cell]  = hi; Al1[p][m * 232 + cell]  = lo;
                        }
                    }
            }
        } else {
            // wave 7: load x(t+1) and write into A0[pn] (read next at t+1)
            if (t + 1 < Tmax) {
#pragma unroll
                for (int i = 0; i < 7; ++i)
                    if (xvalid[i]) xv[i] = x[xg[i] + (size_t)(t + 1) * F_];
#pragma unroll
                for (int i = 0; i < 7; ++i) if (xvalid[i]) {
                    unsigned short hi, lo; split_bf16(xv[i], hi, lo);
                    Ah0[pn][xa[i]] = hi; Al0[pn][xa[i]] = lo;
                }
            }
        }
        __syncthreads();   // (A) h0n published in A1[p]
        // =============== phase 2: layer-1 (reads A1[p]) ===============
        if (wv < 7) {
            f32x4 P[2][4];
#pragma unroll
            for (int mt = 0; mt < 2; ++mt)
#pragma unroll
                for (int g = 0; g < 4; ++g)
                    P[mt][g] = (f32x4){b1v[g], b1v[g], b1v[g], b1v[g]};
            bf16x8 bh[2], bl[2], ah[2], al[2];
            bh[0] = *(const bf16x8*)&B1w[0];
            bl[0] = *(const bf16x8*)&B1w[512];
#pragma unroll
            for (int i = 0; i < 28; ++i) {   // i = kt*4 + g
                const int kt = i >> 2, g = i & 3, cb = i & 1, nb = cb ^ 1;
                if (i + 1 < 28) {
                    bh[nb] = *(const bf16x8*)&B1w[(i + 1) * 7168];
                    bl[nb] = *(const bf16x8*)&B1w[(i + 1) * 7168 + 512];
                }
                if (g == 0) {
#pragma unroll
                    for (int mt = 0; mt < 2; ++mt) {
                        ah[mt] = *(const bf16x8*)&Ah1[p][offA1[mt] + kt * 32];
                        al[mt] = *(const bf16x8*)&Al1[p][offA1[mt] + kt * 32];
                    }
                }
#pragma unroll
                for (int mt = 0; mt < 2; ++mt) {
                    f32x4 acc = P[mt][g];
                    acc = __builtin_amdgcn_mfma_f32_16x16x32_bf16(ah[mt], bl[cb], acc, 0, 0, 0);
                    acc = __builtin_amdgcn_mfma_f32_16x16x32_bf16(al[mt], bh[cb], acc, 0, 0, 0);
                    acc = __builtin_amdgcn_mfma_f32_16x16x32_bf16(ah[mt], bh[cb], acc, 0, 0, 0);
                    P[mt][g] = acc;
                }
            }
            float hreg[8];
#pragma unroll
            for (int mt = 0; mt < 2; ++mt)
#pragma unroll
                for (int r = 0; r < 4; ++r) {
                    float zi = P[mt][0][r];
                    float zf = P[mt][1][r];
                    float zg = P[mt][2][r];
                    float zo = P[mt][3][r];
                    float cn = sigmoid_f(zf) * c1[mt * 4 + r] + sigmoid_f(zi) * tanh_f(zg);
                    float hn = sigmoid_f(zo) * tanh_f(cn);
                    if (t < lenR[mt * 4 + r]) c1[mt * 4 + r] = cn;
                    hreg[mt * 4 + r] = hn;
                }
            // h1n -> A1[pn] (read at t+1); frozen rows keep last value in
            // buffer (len&1)
            if (cell < 100) {
#pragma unroll
                for (int mt = 0; mt < 2; ++mt)
#pragma unroll
                    for (int r = 0; r < 4; ++r) {
                        if (t < lenR[mt * 4 + r]) {
                            int m = mt * 16 + q * 4 + r;
                            unsigned short hi, lo; split_bf16(hreg[mt * 4 + r], hi, lo);
                            Ah1[pn][m * 232 + 100 + cell] = hi;
                            Al1[pn][m * 232 + 100 + cell] = lo;
                        }
                    }
            }
        }
        __syncthreads();   // (B) A0[pn] (h0n+x) and A1[pn] (h1n) published
    }

    // final: out[b] = W_fc . h1 + b_fc  (h1 = hi+lo, frozen at len-1; it lives
    // in buffer len&1 since the last write at t=len-1 targeted parity (len-1)^1)
    if (tid < 32) {
        const int par = sLen[tid] & 1;
        float s = bfc[0];
        for (int j = 0; j < 100; ++j) {
            float h = bf16_to_f(Ah1[par][tid * 232 + 100 + j]) +
                      bf16_to_f(Al1[par][tid * 232 + 100 + j]);
            s = fmaf(Wfc[j], h, s);
        }
        out[sRow[tid]] = s;
    }
}

// ---------------- launch ----------------
extern "C" void kernel_launch(void* const* d_in, const int* in_sizes, int n_in,
                              void* d_out, int out_size, void* d_ws, size_t ws_size,
                              hipStream_t stream) {
    const float* x    = (const float*)d_in[0];
    const int*   len  = (const int*)d_in[1];
    const float* Wih0 = (const float*)d_in[2];
    const float* Whh0 = (const float*)d_in[3];
    const float* bih0 = (const float*)d_in[4];
    const float* bhh0 = (const float*)d_in[5];
    const float* Wih1 = (const float*)d_in[6];
    const float* Whh1 = (const float*)d_in[7];
    const float* bih1 = (const float*)d_in[8];
    const float* bhh1 = (const float*)d_in[9];
    const float* Wfc  = (const float*)d_in[10];
    const float* bfc  = (const float*)d_in[11];
    float* out = (float*)d_out;

    char* ws = (char*)d_ws;   // uses 651,264 bytes
    int*            hist   = (int*)(ws + O_HIST);
    int*            rowmap = (int*)(ws + O_ROWMAP);
    float*          bias0  = (float*)(ws + O_BIAS0);
    float*          bias1  = (float*)(ws + O_BIAS1);
    unsigned short* B0     = (unsigned short*)(ws + O_B0);
    unsigned short* B1     = (unsigned short*)(ws + O_B1);

    hipMemsetAsync(hist, 0, 512, stream);
    k_hist<<<16, 256, 0, stream>>>(len, hist);
    k_scan<<<1, 64, 0, stream>>>(hist);
    k_scatter<<<16, 256, 0, stream>>>(len, hist, rowmap);
    k_prep_bias<<<2, 256, 0, stream>>>(bih0, bhh0, bih1, bhh1, bias0, bias1);
    k_prep_b<<<(7 * 28672 + 255) / 256, 256, 0, stream>>>(Wih0, Whh0, Wih1, Whh1, B0, B1);
    k_lstm<<<128, 512, 0, stream>>>(x, len, rowmap, B0, B1, bias0, bias1, Wfc, bfc, out);
}

// Round 3
// 1053.512 us; speedup vs baseline: 2.6717x; 1.6773x over previous
//
#include <hip/hip_runtime.h>
#include <math.h>

// Problem constants (B=4096, T=100, F=13, H=100)
#define B_    4096
#define T_    100
#define F_    13
#define H_    100

typedef short bf16x8 __attribute__((ext_vector_type(8)));
typedef float f32x4  __attribute__((ext_vector_type(4)));

// ---- ws layout (bytes), total 651,264 ----
#define O_HIST   0u        // 512
#define O_ROWMAP 512u      // 4096*4
#define O_BIAS0  16896u    // 448*4
#define O_BIAS1  18688u    // 448*4
#define O_B0     20480u    // 4kt * 28672 u16 * 2B = 229376
#define O_B1     249856u   // 7kt * 28672 u16 * 2B = 401408 -> 651264

// B-fragment array layout (u16 units), per layer:
//   idx = (((kt*4 + g)*7 + ct)*2 + pass)*512 + lane*8 + j
// where lane's frag element j holds W_pass[k = kt*32 + (lane>>4)*8 + j]
//                                  [col = g*112 + ct*16 + (lane&15)]
// (cols are gate-major with H padded 100->112; pad cols/k are zero)

__device__ __forceinline__ float sigmoid_f(float v) {
    return 1.0f / (1.0f + __expf(-v));
}
__device__ __forceinline__ float tanh_f(float v) {
    float e = __expf(2.0f * v);
    return 1.0f - 2.0f / (e + 1.0f);
}
// fp32 -> bf16 hi (truncate) + lo (RNE of remainder): hi+lo ~ 2^-17 rel err
__device__ __forceinline__ void split_bf16(float v, unsigned short& hi, unsigned short& lo) {
    unsigned u = __float_as_uint(v);
    hi = (unsigned short)(u >> 16);
    float hf = __uint_as_float(u & 0xFFFF0000u);
    float rem = v - hf;
    unsigned r = __float_as_uint(rem);
    unsigned rnd = r + 0x7FFFu + ((r >> 16) & 1u);
    lo = (unsigned short)(rnd >> 16);
}
__device__ __forceinline__ float bf16_to_f(unsigned short b) {
    return __uint_as_float(((unsigned)b) << 16);
}

// ---------------- prep: counting sort of rows by length ----------------
__global__ void k_hist(const int* __restrict__ len, int* __restrict__ hist) {
    int b = blockIdx.x * blockDim.x + threadIdx.x;
    if (b < B_) atomicAdd(&hist[len[b]], 1);
}
__global__ void k_scan(int* __restrict__ hist) {
    if (threadIdx.x == 0 && blockIdx.x == 0) {
        int acc = 0;
        for (int l = 0; l <= 100; ++l) { int c = hist[l]; hist[l] = acc; acc += c; }
    }
}
__global__ void k_scatter(const int* __restrict__ len, int* __restrict__ hist,
                          int* __restrict__ rowmap) {
    int b = blockIdx.x * blockDim.x + threadIdx.x;
    if (b < B_) {
        int pos = atomicAdd(&hist[len[b]], 1);
        rowmap[pos] = b;
    }
}

// ---------------- prep: biases (gate-major, padded) ----------------
__global__ void k_prep_bias(const float* __restrict__ bih0, const float* __restrict__ bhh0,
                            const float* __restrict__ bih1, const float* __restrict__ bhh1,
                            float* __restrict__ bias0, float* __restrict__ bias1) {
    int idx = blockIdx.x * blockDim.x + threadIdx.x;
    if (idx < 448) {
        int g = idx / 112, cell = idx % 112;
        float v0 = 0.f, v1 = 0.f;
        if (cell < 100) {
            int row = g * 100 + cell;
            v0 = bih0[row] + bhh0[row];
            v1 = bih1[row] + bhh1[row];
        }
        bias0[idx] = v0; bias1[idx] = v1;
    }
}

// ---------------- prep: weights into B-fragment order, bf16 hi/lo ----------
// Layer0 A-k: k<100 -> h0 (Whh0), 100..112 -> x (Wih0), >=113 -> 0
// Layer1 A-k: k<100 -> h0n (Wih1), 100..199 -> h1 (Whh1), >=200 -> 0
__global__ void k_prep_b(const float* __restrict__ Wih0, const float* __restrict__ Whh0,
                         const float* __restrict__ Wih1, const float* __restrict__ Whh1,
                         unsigned short* __restrict__ B0, unsigned short* __restrict__ B1) {
    const int PER_KT = 4 * 7 * 2 * 512;  // 28672 u16 per K-tile
    int idx = blockIdx.x * blockDim.x + threadIdx.x;
    if (idx >= 7 * PER_KT) return;
    int kt = idx / PER_KT;
    int s  = idx % PER_KT;
    int g  = s / 7168;
    int s2 = s % 7168;
    int ct = s2 / 1024;
    int s3 = s2 % 1024;
    int pass = s3 / 512;
    int e  = s3 % 512;
    int lane = e >> 3, j = e & 7;
    int n = lane & 15, q = lane >> 4;
    int k = kt * 32 + q * 8 + j;
    int cell = ct * 16 + n;

    unsigned short hi, lo;
    {   // layer 1
        float w = 0.f;
        if (cell < 100) {
            int row = g * 100 + cell;
            if (k < 100)      w = Wih1[row * 100 + k];
            else if (k < 200) w = Whh1[row * 100 + (k - 100)];
        }
        split_bf16(w, hi, lo);
        B1[idx] = pass ? lo : hi;
    }
    if (kt < 4) {  // layer 0
        float w = 0.f;
        if (cell < 100) {
            int row = g * 100 + cell;
            if (k < 100)      w = Whh0[row * 100 + k];
            else if (k < 113) w = Wih0[row * 13 + (k - 100)];
        }
        split_bf16(w, hi, lo);
        B0[idx] = pass ? lo : hi;
    }
}

// ---------------- main persistent MFMA LSTM ----------------
// v4: 256 blocks x 16 rows (was 128 x 32) -> all 256 CUs active.
//  * Per-CU MFMA and pointwise-VALU work halves; B-fragment L2 streaming per
//    block is unchanged (it is per-wave, M-independent), so the aggregate L2
//    floor is the same — but the compute half of the critical path shrinks and
//    chip-wide latency-hiding doubles.
//  * Single M-tile: accumulators 16 VGPR, A-frags 8 -> demand ~90 regs, far
//    below the 128 cap (no spill risk; slack lets the compiler pipeline the
//    B-frag prefetch deeper).
//  * Keeps v3's verified schedule: single chained accumulator (3 MFMA/frag),
//    flattened (kt,g) loop with 1-deep B double-buffer, double-buffered LDS
//    A-state with 2 barriers/step, parity readout.
// Waves 0..6: cell-tile ct (cells 16ct..16ct+15), all 4 gates. Wave 7: x.
__global__ __attribute__((amdgpu_flat_work_group_size(512, 512), amdgpu_waves_per_eu(2, 2)))
void k_lstm(
    const float* __restrict__ x, const int* __restrict__ lengths,
    const int* __restrict__ rowmap,
    const unsigned short* __restrict__ B0, const unsigned short* __restrict__ B1,
    const float* __restrict__ bias0, const float* __restrict__ bias1,
    const float* __restrict__ Wfc, const float* __restrict__ bfc,
    float* __restrict__ out)
{
    // strides padded (+8 u16) so frag reads are 2-way-conflict max (free)
    __shared__ __align__(16) unsigned short Ah0[2][16 * 136];
    __shared__ __align__(16) unsigned short Al0[2][16 * 136];
    __shared__ __align__(16) unsigned short Ah1[2][16 * 232];
    __shared__ __align__(16) unsigned short Al1[2][16 * 232];
    __shared__ int sRow[16], sLen[16], sTmax;

    const int tid = threadIdx.x;
    const int wv = tid >> 6, lane = tid & 63;

    if (tid < 16) {
        int r = rowmap[blockIdx.x * 16 + tid];
        sRow[tid] = r; sLen[tid] = lengths[r];
    }
    for (int i = tid; i < 16 * 136; i += 512) {
        Ah0[0][i] = 0; Al0[0][i] = 0; Ah0[1][i] = 0; Al0[1][i] = 0;
    }
    for (int i = tid; i < 16 * 232; i += 512) {
        Ah1[0][i] = 0; Al1[0][i] = 0; Ah1[1][i] = 0; Al1[1][i] = 0;
    }
    __syncthreads();   // (pre-1) sRow/sLen + zero-init published
    if (tid == 0) { int m = 0; for (int i = 0; i < 16; ++i) m = max(m, sLen[i]); sTmax = m; }

    // ---- per-wave setup ----
    const int ct = wv, n = lane & 15, q = lane >> 4;
    const int cell = ct * 16 + n;

    float b0v[4], b1v[4];
    int   lenR[4];
    float c0[4], c1[4];
    int offA0, offA1;
    const unsigned short* B0w = B0 + ct * 1024 + lane * 8;
    const unsigned short* B1w = B1 + ct * 1024 + lane * 8;
    if (wv < 7) {
#pragma unroll
        for (int g = 0; g < 4; ++g) {
            b0v[g] = bias0[g * 112 + cell];
            b1v[g] = bias1[g * 112 + cell];
        }
        offA0 = n * 136 + q * 8;
        offA1 = n * 232 + q * 8;
#pragma unroll
        for (int r = 0; r < 4; ++r) {
            lenR[r] = sLen[q * 4 + r];       // C row = q*4 + r
            c0[r] = 0.f; c1[r] = 0.f;
        }
    }

    // wave 7: x loader (16 rows x 13 feats = 208 slots, 4 per lane)
    int xvalid[4]; size_t xg[4]; int xa[4]; float xv[4];
    if (wv == 7) {
#pragma unroll
        for (int i = 0; i < 4; ++i) {
            int e = i * 64 + lane;
            xvalid[i] = (e < 208);
            int r = xvalid[i] ? (e / 13) : 0;
            int f = xvalid[i] ? (e - 13 * r) : 0;
            xg[i] = (size_t)sRow[r] * (T_ * F_) + f;
            xa[i] = r * 136 + 100 + f;
            xv[i] = xvalid[i] ? x[xg[i]] : 0.f;   // t = 0
        }
    }
    __syncthreads();   // (pre-2) sTmax published; zero-init done everywhere
    const int Tmax = sTmax;
    if (wv == 7) {     // write x_0 into buffer 0
#pragma unroll
        for (int i = 0; i < 4; ++i) if (xvalid[i]) {
            unsigned short hi, lo; split_bf16(xv[i], hi, lo);
            Ah0[0][xa[i]] = hi; Al0[0][xa[i]] = lo;
        }
    }
    __syncthreads();   // (pre-3) x_0 published

    for (int t = 0; t < Tmax; ++t) {
        const int p = t & 1, pn = p ^ 1;
        // =============== phase 1: layer-0 (reads A0[p]) ===============
        if (wv < 7) {
            f32x4 P[4];
#pragma unroll
            for (int g = 0; g < 4; ++g)
                P[g] = (f32x4){b0v[g], b0v[g], b0v[g], b0v[g]};
            bf16x8 bh[2], bl[2], ah, al;
            bh[0] = *(const bf16x8*)&B0w[0];
            bl[0] = *(const bf16x8*)&B0w[512];
#pragma unroll
            for (int i = 0; i < 16; ++i) {   // i = kt*4 + g
                const int kt = i >> 2, g = i & 3, cb = i & 1, nb = cb ^ 1;
                if (i + 1 < 16) {
                    bh[nb] = *(const bf16x8*)&B0w[(i + 1) * 7168];
                    bl[nb] = *(const bf16x8*)&B0w[(i + 1) * 7168 + 512];
                }
                if (g == 0) {
                    ah = *(const bf16x8*)&Ah0[p][offA0 + kt * 32];
                    al = *(const bf16x8*)&Al0[p][offA0 + kt * 32];
                }
                f32x4 acc = P[g];
                acc = __builtin_amdgcn_mfma_f32_16x16x32_bf16(ah, bl[cb], acc, 0, 0, 0);
                acc = __builtin_amdgcn_mfma_f32_16x16x32_bf16(al, bh[cb], acc, 0, 0, 0);
                acc = __builtin_amdgcn_mfma_f32_16x16x32_bf16(ah, bh[cb], acc, 0, 0, 0);
                P[g] = acc;
            }
            // pointwise + state update
            float hreg[4];
#pragma unroll
            for (int r = 0; r < 4; ++r) {
                float zi = P[0][r];
                float zf = P[1][r];
                float zg = P[2][r];
                float zo = P[3][r];
                float cn = sigmoid_f(zf) * c0[r] + sigmoid_f(zi) * tanh_f(zg);
                float hn = sigmoid_f(zo) * tanh_f(cn);
                if (t < lenR[r]) c0[r] = cn;
                hreg[r] = hn;
            }
            // h0n -> A0[pn] (for GEMM0 at t+1) and A1[p] (for GEMM1 this step)
            if (cell < 100) {
#pragma unroll
                for (int r = 0; r < 4; ++r) {
                    if (t < lenR[r]) {
                        int m = q * 4 + r;
                        unsigned short hi, lo; split_bf16(hreg[r], hi, lo);
                        Ah0[pn][m * 136 + cell] = hi; Al0[pn][m * 136 + cell] = lo;
                        Ah1[p][m * 232 + cell]  = hi; Al1[p][m * 232 + cell]  = lo;
                    }
                }
            }
        } else {
            // wave 7: load x(t+1) and write into A0[pn] (read next at t+1)
            if (t + 1 < Tmax) {
#pragma unroll
                for (int i = 0; i < 4; ++i)
                    if (xvalid[i]) xv[i] = x[xg[i] + (size_t)(t + 1) * F_];
#pragma unroll
                for (int i = 0; i < 4; ++i) if (xvalid[i]) {
                    unsigned short hi, lo; split_bf16(xv[i], hi, lo);
                    Ah0[pn][xa[i]] = hi; Al0[pn][xa[i]] = lo;
                }
            }
        }
        __syncthreads();   // (A) h0n published in A1[p]
        // =============== phase 2: layer-1 (reads A1[p]) ===============
        if (wv < 7) {
            f32x4 P[4];
#pragma unroll
            for (int g = 0; g < 4; ++g)
                P[g] = (f32x4){b1v[g], b1v[g], b1v[g], b1v[g]};
            bf16x8 bh[2], bl[2], ah, al;
            bh[0] = *(const bf16x8*)&B1w[0];
            bl[0] = *(const bf16x8*)&B1w[512];
#pragma unroll
            for (int i = 0; i < 28; ++i) {   // i = kt*4 + g
                const int kt = i >> 2, g = i & 3, cb = i & 1, nb = cb ^ 1;
                if (i + 1 < 28) {
                    bh[nb] = *(const bf16x8*)&B1w[(i + 1) * 7168];
                    bl[nb] = *(const bf16x8*)&B1w[(i + 1) * 7168 + 512];
                }
                if (g == 0) {
                    ah = *(const bf16x8*)&Ah1[p][offA1 + kt * 32];
                    al = *(const bf16x8*)&Al1[p][offA1 + kt * 32];
                }
                f32x4 acc = P[g];
                acc = __builtin_amdgcn_mfma_f32_16x16x32_bf16(ah, bl[cb], acc, 0, 0, 0);
                acc = __builtin_amdgcn_mfma_f32_16x16x32_bf16(al, bh[cb], acc, 0, 0, 0);
                acc = __builtin_amdgcn_mfma_f32_16x16x32_bf16(ah, bh[cb], acc, 0, 0, 0);
                P[g] = acc;
            }
            float hreg[4];
#pragma unroll
            for (int r = 0; r < 4; ++r) {
                float zi = P[0][r];
                float zf = P[1][r];
                float zg = P[2][r];
                float zo = P[3][r];
                float cn = sigmoid_f(zf) * c1[r] + sigmoid_f(zi) * tanh_f(zg);
                float hn = sigmoid_f(zo) * tanh_f(cn);
                if (t < lenR[r]) c1[r] = cn;
                hreg[r] = hn;
            }
            // h1n -> A1[pn] (read at t+1); frozen rows keep last value in
            // buffer (len&1)
            if (cell < 100) {
#pragma unroll
                for (int r = 0; r < 4; ++r) {
                    if (t < lenR[r]) {
                        int m = q * 4 + r;
                        unsigned short hi, lo; split_bf16(hreg[r], hi, lo);
                        Ah1[pn][m * 232 + 100 + cell] = hi;
                        Al1[pn][m * 232 + 100 + cell] = lo;
                    }
                }
            }
        }
        __syncthreads();   // (B) A0[pn] (h0n+x) and A1[pn] (h1n) published
    }

    // final: out[b] = W_fc . h1 + b_fc  (h1 = hi+lo, frozen at len-1; it lives
    // in buffer len&1 since the last write at t=len-1 targeted parity (len-1)^1)
    if (tid < 16) {
        const int par = sLen[tid] & 1;
        float s = bfc[0];
        for (int j = 0; j < 100; ++j) {
            float h = bf16_to_f(Ah1[par][tid * 232 + 100 + j]) +
                      bf16_to_f(Al1[par][tid * 232 + 100 + j]);
            s = fmaf(Wfc[j], h, s);
        }
        out[sRow[tid]] = s;
    }
}

// ---------------- launch ----------------
extern "C" void kernel_launch(void* const* d_in, const int* in_sizes, int n_in,
                              void* d_out, int out_size, void* d_ws, size_t ws_size,
                              hipStream_t stream) {
    const float* x    = (const float*)d_in[0];
    const int*   len  = (const int*)d_in[1];
    const float* Wih0 = (const float*)d_in[2];
    const float* Whh0 = (const float*)d_in[3];
    const float* bih0 = (const float*)d_in[4];
    const float* bhh0 = (const float*)d_in[5];
    const float* Wih1 = (const float*)d_in[6];
    const float* Whh1 = (const float*)d_in[7];
    const float* bih1 = (const float*)d_in[8];
    const float* bhh1 = (const float*)d_in[9];
    const float* Wfc  = (const float*)d_in[10];
    const float* bfc  = (const float*)d_in[11];
    float* out = (float*)d_out;

    char* ws = (char*)d_ws;   // uses 651,264 bytes
    int*            hist   = (int*)(ws + O_HIST);
    int*            rowmap = (int*)(ws + O_ROWMAP);
    float*          bias0  = (float*)(ws + O_BIAS0);
    float*          bias1  = (float*)(ws + O_BIAS1);
    unsigned short* B0     = (unsigned short*)(ws + O_B0);
    unsigned short* B1     = (unsigned short*)(ws + O_B1);

    hipMemsetAsync(hist, 0, 512, stream);
    k_hist<<<16, 256, 0, stream>>>(len, hist);
    k_scan<<<1, 64, 0, stream>>>(hist);
    k_scatter<<<16, 256, 0, stream>>>(len, hist, rowmap);
    k_prep_bias<<<2, 256, 0, stream>>>(bih0, bhh0, bih1, bhh1, bias0, bias1);
    k_prep_b<<<(7 * 28672 + 255) / 256, 256, 0, stream>>>(Wih0, Whh0, Wih1, Whh1, B0, B1);
    k_lstm<<<256, 512, 0, stream>>>(x, len, rowmap, B0, B1, bias0, bias1, Wfc, bfc, out);
}